// Round 1
// baseline (344.733 us; speedup 1.0000x reference)
//
#include <hip/hip_runtime.h>
#include <math.h>

#define NQ 16
#define NL 5
#define NB 64
#define NC 10
#define TSIZE 8192     // amplitudes per tile (2^13)
#define NTILES 8
#define THREADS 512

__device__ __forceinline__ float2 cmul(float2 a, float2 b) {
  return make_float2(a.x*b.x - a.y*b.y, a.x*b.y + a.y*b.x);
}
__device__ __forceinline__ float2 cadd(float2 a, float2 b) {
  return make_float2(a.x + b.x, a.y + b.y);
}

// ---------------- precompute: fused U = Rot(phi,theta,omega) * RX(x) per (b, layer, wire);
// ---------------- CRX cos/sin per (layer, wire)
__global__ void precompute_kernel(const float* __restrict__ x, const float* __restrict__ rot,
                                  const float* __restrict__ crx,
                                  float2* __restrict__ gates1q, float2* __restrict__ crxcs) {
  int idx = blockIdx.x * blockDim.x + threadIdx.x;
  if (idx < NB * NL * NQ) {
    int w = idx % NQ; int n = (idx / NQ) % NL; int b = idx / (NQ * NL);
    float xv = x[b * NQ + w];
    float sx, cx; sincosf(0.5f * xv, &sx, &cx);
    float phi = rot[(n * NQ + w) * 3 + 0];
    float th  = rot[(n * NQ + w) * 3 + 1];
    float om  = rot[(n * NQ + w) * 3 + 2];
    float st, ct; sincosf(0.5f * th, &st, &ct);
    float sa, ca; sincosf(0.5f * (phi + om), &sa, &ca);
    float sd, cd; sincosf(0.5f * (phi - om), &sd, &cd);
    // Rot = [[ep*ct, -conj(em)*st],[em*st, conj(ep)*ct]], ep=e^{-i(phi+om)/2}, em=e^{-i(phi-om)/2}
    float2 r00 = make_float2( ca * ct, -sa * ct);
    float2 r01 = make_float2(-cd * st, -sd * st);
    float2 r10 = make_float2( cd * st, -sd * st);
    float2 r11 = make_float2( ca * ct,  sa * ct);
    // RX = [[cx, -i sx],[-i sx, cx]]
    float2 rc = make_float2(cx, 0.f), rs = make_float2(0.f, -sx);
    float2* dst = gates1q + (size_t)idx * 4;
    dst[0] = cadd(cmul(r00, rc), cmul(r01, rs));
    dst[1] = cadd(cmul(r00, rs), cmul(r01, rc));
    dst[2] = cadd(cmul(r10, rc), cmul(r11, rs));
    dst[3] = cadd(cmul(r10, rs), cmul(r11, rc));
  }
  int c = idx - NB * NL * NQ;
  if (c >= 0 && c < NL * NQ) {
    float s, cc; sincosf(0.5f * crx[c], &s, &cc);
    crxcs[c] = make_float2(cc, s);
  }
}

// ---------------- in-register group gate primitives ----------------
// apply 2x2 gate U (u00,u01,u10,u11) on group-bit GB of a 2^K-amplitude register group
template<int K, int GB>
__device__ __forceinline__ void g1q(float2* v, const float2* U) {
  #pragma unroll
  for (int m = 0; m < (1 << K); ++m) {
    if (!(m & (1 << GB))) {
      const int m2 = m | (1 << GB);
      float2 a = v[m], b = v[m2];
      v[m]  = cadd(cmul(U[0], a), cmul(U[1], b));
      v[m2] = cadd(cmul(U[2], a), cmul(U[3], b));
    }
  }
}

// controlled-RX: control group-bit CP, target group-bit TP, RX = [[c,-is],[-is,c]]
template<int K, int CP, int TP>
__device__ __forceinline__ void gcrx(float2* v, float c, float s) {
  #pragma unroll
  for (int m = 0; m < (1 << K); ++m) {
    if ((m & (1 << CP)) && !(m & (1 << TP))) {
      const int m2 = m | (1 << TP);
      float2 a = v[m], b = v[m2];
      v[m]  = make_float2(c * a.x + s * b.y, c * a.y - s * b.x);
      v[m2] = make_float2(c * b.x + s * a.y, c * b.y - s * a.x);
    }
  }
}

template<int Bb>
__device__ __forceinline__ int ins0(int v) {
  return ((v >> Bb) << (Bb + 1)) | (v & ((1 << Bb) - 1));
}

// sweep all 2^13 LDS amplitudes in groups spanning bits {B0<B1<B2<B3} (first K used),
// applying functor f to each 2^K register group. Barrier at end.
template<int K, int B0, int B1, int B2, int B3, class F>
__device__ __forceinline__ void sweepK(float2* __restrict__ amp, F f) {
  constexpr int PER = 1 << K;
  for (int p = threadIdx.x; p < (TSIZE >> K); p += THREADS) {
    int base = ins0<B0>(p);
    if constexpr (K > 1) base = ins0<B1>(base);
    if constexpr (K > 2) base = ins0<B2>(base);
    if constexpr (K > 3) base = ins0<B3>(base);
    float2 v[PER];
    #pragma unroll
    for (int m = 0; m < PER; ++m) {
      int off = ((m & 1) ? (1 << B0) : 0);
      if constexpr (K > 1) { if (m & 2) off |= (1 << B1); }
      if constexpr (K > 2) { if (m & 4) off |= (1 << B2); }
      if constexpr (K > 3) { if (m & 8) off |= (1 << B3); }
      v[m] = amp[base + off];
    }
    f(v);
    #pragma unroll
    for (int m = 0; m < PER; ++m) {
      int off = ((m & 1) ? (1 << B0) : 0);
      if constexpr (K > 1) { if (m & 2) off |= (1 << B1); }
      if constexpr (K > 2) { if (m & 4) off |= (1 << B2); }
      if constexpr (K > 3) { if (m & 8) off |= (1 << B3); }
      amp[base + off] = v[m];
    }
  }
  __syncthreads();
}

__device__ __forceinline__ void loadU(const float2* __restrict__ G, int w, float2* U) {
  const float4* p = (const float4*)(G + w * 4);
  float4 a = p[0], b = p[1];
  U[0] = make_float2(a.x, a.y); U[1] = make_float2(a.z, a.w);
  U[2] = make_float2(b.x, b.y); U[3] = make_float2(b.z, b.w);
}

// PASS 0 (A): excluded/tile bits {13,14,15}; local bit of wire w is w (w<=12)
// PASS 1 (B): excluded/tile bits {9,10,11}; local bit: w<9 -> w; w>=12 -> w-3
template<int PASS>
__device__ __forceinline__ int expand_tile(int l, int t) {
  if constexpr (PASS == 0) return (t << 13) | l;
  else return ((l >> 9) << 12) | (t << 9) | (l & 511);
}

template<int LAYER, bool FIRST, bool LAST, int PASS>
__global__ __launch_bounds__(THREADS)
void pass_kernel(const float2* __restrict__ gates1q, const float2* __restrict__ crxcs,
                 float2* __restrict__ state, float* __restrict__ zpart) {
  __shared__ __align__(16) float2 amp[TSIZE];   // 64 KB
  const int b = blockIdx.x >> 3, t = blockIdx.x & 7;
  const float2* G  = gates1q + (size_t)(b * NL + LAYER) * NQ * 4;
  const float2* CS = crxcs + LAYER * NQ;
  float4* amp4 = (float4*)amp;
  float4* st4  = (float4*)state;
  const size_t sbase = ((size_t)b << 16);

  // ---- load tile (or generate |0...0>) ----
  if constexpr (FIRST) {
    for (int j = threadIdx.x; j < TSIZE / 2; j += THREADS) amp4[j] = make_float4(0.f, 0.f, 0.f, 0.f);
    if (t == 0 && threadIdx.x == 0) amp[0] = make_float2(1.f, 0.f);
  } else {
    for (int j = threadIdx.x; j < TSIZE / 2; j += THREADS) {
      int l = j << 1;
      int g = expand_tile<PASS>(l, t);
      amp4[j] = st4[(sbase + (size_t)g) >> 1];
    }
  }
  __syncthreads();

  // ---- gates ----
  float2 U0[4], U1[4], U2[4], U3[4];
  if constexpr (PASS == 0) {
    // fused 1q (Rot*RX) wires 0..11, 4 per sweep
    loadU(G, 0, U0); loadU(G, 1, U1); loadU(G, 2, U2); loadU(G, 3, U3);
    sweepK<4, 0, 1, 2, 3>(amp, [&](float2* v) {
      g1q<4,0>(v, U0); g1q<4,1>(v, U1); g1q<4,2>(v, U2); g1q<4,3>(v, U3); });
    loadU(G, 4, U0); loadU(G, 5, U1); loadU(G, 6, U2); loadU(G, 7, U3);
    sweepK<4, 4, 5, 6, 7>(amp, [&](float2* v) {
      g1q<4,0>(v, U0); g1q<4,1>(v, U1); g1q<4,2>(v, U2); g1q<4,3>(v, U3); });
    loadU(G, 8, U0); loadU(G, 9, U1); loadU(G, 10, U2); loadU(G, 11, U3);
    sweepK<4, 8, 9, 10, 11>(amp, [&](float2* v) {
      g1q<4,0>(v, U0); g1q<4,1>(v, U1); g1q<4,2>(v, U2); g1q<4,3>(v, U3); });
    // CRX chain 0..11 (order preserved), 3 per sweep
    float2 c0 = CS[0], c1 = CS[1], c2 = CS[2];
    sweepK<4, 0, 1, 2, 3>(amp, [&](float2* v) {
      gcrx<4,0,1>(v, c0.x, c0.y); gcrx<4,1,2>(v, c1.x, c1.y); gcrx<4,2,3>(v, c2.x, c2.y); });
    c0 = CS[3]; c1 = CS[4]; c2 = CS[5];
    sweepK<4, 3, 4, 5, 6>(amp, [&](float2* v) {
      gcrx<4,0,1>(v, c0.x, c0.y); gcrx<4,1,2>(v, c1.x, c1.y); gcrx<4,2,3>(v, c2.x, c2.y); });
    c0 = CS[6]; c1 = CS[7]; c2 = CS[8];
    sweepK<4, 6, 7, 8, 9>(amp, [&](float2* v) {
      gcrx<4,0,1>(v, c0.x, c0.y); gcrx<4,1,2>(v, c1.x, c1.y); gcrx<4,2,3>(v, c2.x, c2.y); });
    // 1q wire 12 + CRX(9,10),(10,11),(11,12)
    loadU(G, 12, U0);
    c0 = CS[9]; c1 = CS[10]; c2 = CS[11];
    sweepK<4, 9, 10, 11, 12>(amp, [&](float2* v) {
      g1q<4,3>(v, U0);
      gcrx<4,0,1>(v, c0.x, c0.y); gcrx<4,1,2>(v, c1.x, c1.y); gcrx<4,2,3>(v, c2.x, c2.y); });
  } else {
    // local bits: wire12->9, 13->10, 14->11, 15->12, 0->0
    loadU(G, 13, U0); loadU(G, 14, U1); loadU(G, 15, U2);
    float2 c0 = CS[12], c1 = CS[13], c2 = CS[14], c3 = CS[15];
    sweepK<4, 9, 10, 11, 12>(amp, [&](float2* v) {
      g1q<4,1>(v, U0); g1q<4,2>(v, U1); g1q<4,3>(v, U2);
      gcrx<4,0,1>(v, c0.x, c0.y); gcrx<4,1,2>(v, c1.x, c1.y); gcrx<4,2,3>(v, c2.x, c2.y); });
    // CRX(15,0): control = wire15 = bit12 (group pos 1), target = wire0 = bit0 (group pos 0)
    sweepK<2, 0, 12, 0, 0>(amp, [&](float2* v) { gcrx<2,1,0>(v, c3.x, c3.y); });
  }

  // ---- store tile, or (last pass) Z-expectation partials ----
  if constexpr (!LAST) {
    for (int j = threadIdx.x; j < TSIZE / 2; j += THREADS) {
      int l = j << 1;
      int g = expand_tile<PASS>(l, t);
      st4[(sbase + (size_t)g) >> 1] = amp4[j];
    }
  } else {
    float zacc[16];
    #pragma unroll
    for (int w = 0; w < 16; ++w) zacc[w] = 0.f;
    #pragma unroll
    for (int k = 0; k < 16; ++k) {
      int l = k * THREADS + threadIdx.x;
      float2 a = amp[l];
      float pr = a.x * a.x + a.y * a.y;
      #pragma unroll
      for (int w = 0; w < 16; ++w) {
        int bit;
        if (w < 9)       bit = (l >> w) & 1;         // local bits
        else if (w < 12) bit = (t >> (w - 9)) & 1;   // tile bits
        else             bit = (l >> (w - 3)) & 1;   // local bits shifted past excluded
        zacc[w] += bit ? -pr : pr;
      }
    }
    #pragma unroll
    for (int w = 0; w < 16; ++w) {
      float vv = zacc[w];
      #pragma unroll
      for (int off = 32; off > 0; off >>= 1) vv += __shfl_xor(vv, off);
      zacc[w] = vv;
    }
    __syncthreads();                 // done reading amp; reuse LDS for reduction
    float* red = (float*)amp;
    const int lane = threadIdx.x & 63, wv = threadIdx.x >> 6;
    if (lane == 0) {
      #pragma unroll
      for (int w = 0; w < 16; ++w) red[wv * 16 + w] = zacc[w];
    }
    __syncthreads();
    if (threadIdx.x < 16) {
      float s = 0.f;
      #pragma unroll
      for (int k = 0; k < 8; ++k) s += red[k * 16 + threadIdx.x];
      zpart[blockIdx.x * 16 + threadIdx.x] = s;
    }
  }
}

// ---------------- epilogue: z reduce over tiles, logits, log_softmax ----------------
__global__ __launch_bounds__(64)
void final_kernel(const float* __restrict__ zpart, const float* __restrict__ fc_w,
                  const float* __restrict__ fc_b, float* __restrict__ out) {
  const int b = blockIdx.x, lane = threadIdx.x;
  float z = 0.f;
  if (lane < 16) {
    #pragma unroll
    for (int t = 0; t < NTILES; ++t) z += zpart[(b * NTILES + t) * 16 + lane];
  }
  float acc = (lane < NC) ? fc_b[lane] : -1e30f;
  #pragma unroll
  for (int w = 0; w < 16; ++w) {
    float zw = __shfl(z, w);
    if (lane < NC) acc += fc_w[lane * 16 + w] * zw;
  }
  float m = -1e30f;
  #pragma unroll
  for (int j = 0; j < NC; ++j) m = fmaxf(m, __shfl(acc, j));
  float e = (lane < NC) ? expf(acc - m) : 0.f;
  float s = 0.f;
  #pragma unroll
  for (int j = 0; j < NC; ++j) s += __shfl(e, j);
  if (lane < NC) out[b * NC + lane] = acc - m - logf(s);
}

extern "C" void kernel_launch(void* const* d_in, const int* in_sizes, int n_in,
                              void* d_out, int out_size, void* d_ws, size_t ws_size,
                              hipStream_t stream) {
  const float* x    = (const float*)d_in[0];
  const float* rot  = (const float*)d_in[1];
  const float* crx  = (const float*)d_in[2];
  const float* fc_w = (const float*)d_in[3];
  const float* fc_b = (const float*)d_in[4];
  float* out = (float*)d_out;

  char* ws = (char*)d_ws;
  float2* state   = (float2*)ws;                                     // 33554432 B
  float2* gates1q = (float2*)(ws + 33554432);                        // 163840 B
  float2* crxcs   = (float2*)(ws + 33554432 + 163840);               // 640 B (padded to 1024)
  float*  zpart   = (float*)(ws + 33554432 + 163840 + 1024);         // 32768 B

  precompute_kernel<<<21, 256, 0, stream>>>(x, rot, crx, gates1q, crxcs);

  const int G = NB * NTILES;
  pass_kernel<0, true,  false, 0><<<G, THREADS, 0, stream>>>(gates1q, crxcs, state, zpart);
  pass_kernel<0, false, false, 1><<<G, THREADS, 0, stream>>>(gates1q, crxcs, state, zpart);
  pass_kernel<1, false, false, 0><<<G, THREADS, 0, stream>>>(gates1q, crxcs, state, zpart);
  pass_kernel<1, false, false, 1><<<G, THREADS, 0, stream>>>(gates1q, crxcs, state, zpart);
  pass_kernel<2, false, false, 0><<<G, THREADS, 0, stream>>>(gates1q, crxcs, state, zpart);
  pass_kernel<2, false, false, 1><<<G, THREADS, 0, stream>>>(gates1q, crxcs, state, zpart);
  pass_kernel<3, false, false, 0><<<G, THREADS, 0, stream>>>(gates1q, crxcs, state, zpart);
  pass_kernel<3, false, false, 1><<<G, THREADS, 0, stream>>>(gates1q, crxcs, state, zpart);
  pass_kernel<4, false, false, 0><<<G, THREADS, 0, stream>>>(gates1q, crxcs, state, zpart);
  pass_kernel<4, false, true,  1><<<G, THREADS, 0, stream>>>(gates1q, crxcs, state, zpart);

  final_kernel<<<NB, 64, 0, stream>>>(zpart, fc_w, fc_b, out);
}

// Round 2
// 280.158 us; speedup vs baseline: 1.2305x; 1.2305x over previous
//
#include <hip/hip_runtime.h>
#include <math.h>

#define NQ 16
#define NL 5
#define NB 64
#define NC 10
#define TSIZE 8192     // amplitudes per tile (2^13)
#define NTILES 8
#define THREADS 512

__device__ __forceinline__ float2 cmul(float2 a, float2 b) {
  return make_float2(a.x*b.x - a.y*b.y, a.x*b.y + a.y*b.x);
}
__device__ __forceinline__ float2 cadd(float2 a, float2 b) {
  return make_float2(a.x + b.x, a.y + b.y);
}
// LDS bank-conflict swizzle: phys = idx ^ ((idx>>4)&0xF). For all sweep patterns
// used below this gives 16 distinct bank-pairs per 16 consecutive lanes (b64) —
// minimum aliasing. SW(base|off) == SW(base) ^ SW(off) since base/off bits disjoint.
__device__ __forceinline__ int sw_idx(int i) { return i ^ ((i >> 4) & 0xF); }

// ---------------- precompute: fused U = Rot * RX per (b, layer, wire); CRX cos/sin
__global__ void precompute_kernel(const float* __restrict__ x, const float* __restrict__ rot,
                                  const float* __restrict__ crx,
                                  float2* __restrict__ gates1q, float2* __restrict__ crxcs) {
  int idx = blockIdx.x * blockDim.x + threadIdx.x;
  if (idx < NB * NL * NQ) {
    int w = idx % NQ; int n = (idx / NQ) % NL; int b = idx / (NQ * NL);
    float xv = x[b * NQ + w];
    float sx, cx; sincosf(0.5f * xv, &sx, &cx);
    float phi = rot[(n * NQ + w) * 3 + 0];
    float th  = rot[(n * NQ + w) * 3 + 1];
    float om  = rot[(n * NQ + w) * 3 + 2];
    float st, ct; sincosf(0.5f * th, &st, &ct);
    float sa, ca; sincosf(0.5f * (phi + om), &sa, &ca);
    float sd, cd; sincosf(0.5f * (phi - om), &sd, &cd);
    float2 r00 = make_float2( ca * ct, -sa * ct);
    float2 r01 = make_float2(-cd * st, -sd * st);
    float2 r10 = make_float2( cd * st, -sd * st);
    float2 r11 = make_float2( ca * ct,  sa * ct);
    float2 rc = make_float2(cx, 0.f), rs = make_float2(0.f, -sx);
    float2* dst = gates1q + (size_t)idx * 4;
    dst[0] = cadd(cmul(r00, rc), cmul(r01, rs));
    dst[1] = cadd(cmul(r00, rs), cmul(r01, rc));
    dst[2] = cadd(cmul(r10, rc), cmul(r11, rs));
    dst[3] = cadd(cmul(r10, rs), cmul(r11, rc));
  }
  int c = idx - NB * NL * NQ;
  if (c >= 0 && c < NL * NQ) {
    float s, cc; sincosf(0.5f * crx[c], &s, &cc);
    crxcs[c] = make_float2(cc, s);
  }
}

// ---------------- register-group gate primitives (K=4, 16 amps/thread) ----------------
template<int K, int GB>
__device__ __forceinline__ void g1q(float2* v, const float2* U) {
  #pragma unroll
  for (int m = 0; m < (1 << K); ++m) {
    if (!(m & (1 << GB))) {
      const int m2 = m | (1 << GB);
      float2 a = v[m], b = v[m2];
      v[m]  = cadd(cmul(U[0], a), cmul(U[1], b));
      v[m2] = cadd(cmul(U[2], a), cmul(U[3], b));
    }
  }
}
// CRX with both ctrl (CP) and target (TP) in the group
template<int K, int CP, int TP>
__device__ __forceinline__ void gcrx(float2* v, float c, float s) {
  #pragma unroll
  for (int m = 0; m < (1 << K); ++m) {
    if ((m & (1 << CP)) && !(m & (1 << TP))) {
      const int m2 = m | (1 << TP);
      float2 a = v[m], b = v[m2];
      v[m]  = make_float2(c * a.x + s * b.y, c * a.y - s * b.x);
      v[m2] = make_float2(c * b.x + s * a.y, c * b.y - s * a.x);
    }
  }
}
// plain RX on group-bit TP (used for ctrl-outside-group CRX; pass c=1,s=0 for identity)
template<int K, int TP>
__device__ __forceinline__ void grx1(float2* v, float c, float s) {
  #pragma unroll
  for (int m = 0; m < (1 << K); ++m) {
    if (!(m & (1 << TP))) {
      const int m2 = m | (1 << TP);
      float2 a = v[m], b = v[m2];
      v[m]  = make_float2(c * a.x + s * b.y, c * a.y - s * b.x);
      v[m2] = make_float2(c * b.x + s * a.y, c * b.y - s * a.x);
    }
  }
}

template<int Bb>
__device__ __forceinline__ int ins0(int v) {
  return ((v >> Bb) << (Bb + 1)) | (v & ((1 << Bb) - 1));
}

// one full-LDS sweep: 512 groups of 16 amps over bits {B0<B1<B2<B3}; one group/thread
template<int B0, int B1, int B2, int B3, class F>
__device__ __forceinline__ void sweep4(float2* __restrict__ amp, F f) {
  const int p = threadIdx.x;
  int base = ins0<B0>(p); base = ins0<B1>(base); base = ins0<B2>(base); base = ins0<B3>(base);
  const int sb = sw_idx(base);
  float2 v[16];
  #pragma unroll
  for (int m = 0; m < 16; ++m) {
    const int off = ((m&1)?(1<<B0):0)|((m&2)?(1<<B1):0)|((m&4)?(1<<B2):0)|((m&8)?(1<<B3):0);
    v[m] = amp[sb ^ sw_idx(off)];
  }
  f(v, base);
  #pragma unroll
  for (int m = 0; m < 16; ++m) {
    const int off = ((m&1)?(1<<B0):0)|((m&2)?(1<<B1):0)|((m&4)?(1<<B2):0)|((m&8)?(1<<B3):0);
    amp[sb ^ sw_idx(off)] = v[m];
  }
  __syncthreads();
}

__device__ __forceinline__ void loadU(const float2* __restrict__ G, int w, float2* U) {
  const float4* p = (const float4*)(G + w * 4);
  float4 a = p[0], b = p[1];
  U[0] = make_float2(a.x, a.y); U[1] = make_float2(a.z, a.w);
  U[2] = make_float2(b.x, b.y); U[3] = make_float2(b.z, b.w);
}

// PASS 0 (A): tile bits {13,14,15}; local bit of wire w is w (w<=12)
// PASS 1 (B): tile bits {9,10,11};  local: w<9 -> w; w>=12 -> w-3
template<int PASS>
__device__ __forceinline__ int expand_tile(int l, int t) {
  if constexpr (PASS == 0) return (t << 13) | l;
  else return ((l >> 9) << 12) | (t << 9) | (l & 511);
}

template<int LAYER, bool FIRST, bool LAST, int PASS>
__global__ __launch_bounds__(THREADS, 4)
void pass_kernel(const float2* __restrict__ gates1q, const float2* __restrict__ crxcs,
                 float2* __restrict__ state, float* __restrict__ zpart) {
  __shared__ __align__(16) float2 amp[TSIZE];   // 64 KB
  const int tid = threadIdx.x;
  const int b = blockIdx.x >> 3, t = blockIdx.x & 7;
  const float2* G  = gates1q + (size_t)(b * NL + LAYER) * NQ * 4;
  const float2* CS = crxcs + LAYER * NQ;
  float4* amp4 = (float4*)amp;
  float4* st4  = (float4*)state;
  const size_t sb4 = ((size_t)b << 16) >> 1;   // float4 base index of this batch's state

  if constexpr (PASS == 0) {
    float2 UA[4], UB[4], UC[4], UD[4];
    loadU(G, 0, UA);
    // ---- load tile (fusing 1q(0)) or generate |0...0> (with 1q(0) applied) ----
    if constexpr (FIRST) {
      if (t != 0) {  // gates on bits 0..12 never populate tiles t!=0 from |0..0>
        float4 z4 = make_float4(0.f, 0.f, 0.f, 0.f);
        for (int j = tid; j < TSIZE / 2; j += THREADS)
          st4[sb4 + (size_t)(((t << 13) | (j << 1)) >> 1)] = z4;
        return;
      }
      for (int j = tid; j < TSIZE / 2; j += THREADS) amp4[j] = make_float4(0.f, 0.f, 0.f, 0.f);
      if (tid == 0) { amp[0] = UA[0]; amp[1] = UA[2]; }   // |0>: (u00, u10) on wire0 pair
      __syncthreads();
    } else {
      for (int j = tid; j < TSIZE / 2; j += THREADS) {
        int l = j << 1;
        float4 d = st4[sb4 + (size_t)(((t << 13) | l) >> 1)];
        float2 a  = make_float2(d.x, d.y), bb = make_float2(d.z, d.w);
        float2 na = cadd(cmul(UA[0], a), cmul(UA[1], bb));
        float2 nb = cadd(cmul(UA[2], a), cmul(UA[3], bb));
        int p0 = sw_idx(l);
        amp4[p0 >> 1] = (p0 & 1) ? make_float4(nb.x, nb.y, na.x, na.y)
                                 : make_float4(na.x, na.y, nb.x, nb.y);
      }
      __syncthreads();
    }
    // ---- sweep {0,1,2,3}: 1q(1,2,3) + crx(0,1),(1,2),(2,3) ----
    loadU(G, 1, UB); loadU(G, 2, UC); loadU(G, 3, UD);
    float2 k0 = CS[0], k1 = CS[1], k2 = CS[2];
    sweep4<0, 1, 2, 3>(amp, [&](float2* v, int base) {
      g1q<4,1>(v, UB); g1q<4,2>(v, UC); g1q<4,3>(v, UD);
      gcrx<4,0,1>(v, k0.x, k0.y); gcrx<4,1,2>(v, k1.x, k1.y); gcrx<4,2,3>(v, k2.x, k2.y);
    });
    // ---- sweep {4,5,6,7}: 1q(4..7) + crx(3,4)[ctrl=base bit3] + (4,5),(5,6),(6,7) ----
    loadU(G, 4, UA); loadU(G, 5, UB); loadU(G, 6, UC); loadU(G, 7, UD);
    float2 k3 = CS[3]; k0 = CS[4]; k1 = CS[5]; k2 = CS[6];
    sweep4<4, 5, 6, 7>(amp, [&](float2* v, int base) {
      g1q<4,0>(v, UA); g1q<4,1>(v, UB); g1q<4,2>(v, UC); g1q<4,3>(v, UD);
      bool pd = (base >> 3) & 1;
      grx1<4,0>(v, pd ? k3.x : 1.0f, pd ? k3.y : 0.0f);
      gcrx<4,0,1>(v, k0.x, k0.y); gcrx<4,1,2>(v, k1.x, k1.y); gcrx<4,2,3>(v, k2.x, k2.y);
    });
    // ---- sweep {8,9,10,11}: 1q(8..11) + crx(7,8)[ctrl=base bit7] + (8,9),(9,10),(10,11) ----
    loadU(G, 8, UA); loadU(G, 9, UB); loadU(G, 10, UC); loadU(G, 11, UD);
    k3 = CS[7]; k0 = CS[8]; k1 = CS[9]; k2 = CS[10];
    sweep4<8, 9, 10, 11>(amp, [&](float2* v, int base) {
      g1q<4,0>(v, UA); g1q<4,1>(v, UB); g1q<4,2>(v, UC); g1q<4,3>(v, UD);
      bool pd = (base >> 7) & 1;
      grx1<4,0>(v, pd ? k3.x : 1.0f, pd ? k3.y : 0.0f);
      gcrx<4,0,1>(v, k0.x, k0.y); gcrx<4,1,2>(v, k1.x, k1.y); gcrx<4,2,3>(v, k2.x, k2.y);
    });
    // ---- store ----
    for (int j = tid; j < TSIZE / 2; j += THREADS) {
      int l = j << 1;
      int p0 = sw_idx(l);
      float4 d = amp4[p0 >> 1];
      if (p0 & 1) d = make_float4(d.z, d.w, d.x, d.y);
      st4[sb4 + (size_t)(((t << 13) | l) >> 1)] = d;
    }
  } else {
    // ================= PASS B =================
    for (int j = tid; j < TSIZE / 2; j += THREADS) {
      int l = j << 1;
      float4 d = st4[sb4 + (size_t)(expand_tile<1>(l, t) >> 1)];
      int p0 = sw_idx(l);
      if (p0 & 1) d = make_float4(d.z, d.w, d.x, d.y);
      amp4[p0 >> 1] = d;
    }
    __syncthreads();
    // ---- sweep {9,10,11,12}: 1q(w12..w15) + crx(11,12)[ctrl=t bit2] + (12,13),(13,14),(14,15) ----
    float2 UA[4], UB[4], UC[4], UD[4];
    loadU(G, 12, UA); loadU(G, 13, UB); loadU(G, 14, UC); loadU(G, 15, UD);
    float2 kB = CS[11], k0 = CS[12], k1 = CS[13], k2 = CS[14], kF = CS[15];
    const bool t2 = (t >> 2) & 1;
    sweep4<9, 10, 11, 12>(amp, [&](float2* v, int base) {
      g1q<4,0>(v, UA); g1q<4,1>(v, UB); g1q<4,2>(v, UC); g1q<4,3>(v, UD);
      grx1<4,0>(v, t2 ? kB.x : 1.0f, t2 ? kB.y : 0.0f);
      gcrx<4,0,1>(v, k0.x, k0.y); gcrx<4,1,2>(v, k1.x, k1.y); gcrx<4,2,3>(v, k2.x, k2.y);
    });
    if constexpr (!LAST) {
      // ---- store with fused crx(15,0): ctrl = local bit12 (wire15), target = pair bit0 ----
      for (int j = tid; j < TSIZE / 2; j += THREADS) {
        int l = j << 1;
        int p0 = sw_idx(l);
        float4 d = amp4[p0 >> 1];
        if (p0 & 1) d = make_float4(d.z, d.w, d.x, d.y);
        if (l & (1 << 12)) {
          float2 a = make_float2(d.x, d.y), bb = make_float2(d.z, d.w);
          d = make_float4(kF.x * a.x + kF.y * bb.y, kF.x * a.y - kF.y * bb.x,
                          kF.x * bb.x + kF.y * a.y, kF.x * bb.y - kF.y * a.x);
        }
        st4[sb4 + (size_t)(expand_tile<1>(l, t) >> 1)] = d;
      }
    } else {
      // ---- final: fused crx(15,0) + Z-expectation partials; no state store ----
      float zacc[16];
      #pragma unroll
      for (int w = 0; w < 16; ++w) zacc[w] = 0.f;
      #pragma unroll
      for (int it = 0; it < 8; ++it) {
        int j = it * THREADS + tid;
        int l = j << 1;
        int p0 = sw_idx(l);
        float4 d = amp4[p0 >> 1];
        if (p0 & 1) d = make_float4(d.z, d.w, d.x, d.y);
        if (l & (1 << 12)) {
          float2 a = make_float2(d.x, d.y), bb = make_float2(d.z, d.w);
          d = make_float4(kF.x * a.x + kF.y * bb.y, kF.x * a.y - kF.y * bb.x,
                          kF.x * bb.x + kF.y * a.y, kF.x * bb.y - kF.y * a.x);
        }
        float pr0 = d.x * d.x + d.y * d.y;
        float pr1 = d.z * d.z + d.w * d.w;
        float prs = pr0 + pr1;
        zacc[0] += pr0 - pr1;                      // wire0 = local bit0 = the pair
        #pragma unroll
        for (int w = 1; w < 16; ++w) {
          int bit;
          if (w < 9)       bit = (l >> w) & 1;       // wires 1..8 -> bits 1..8
          else if (w < 12) bit = (t >> (w - 9)) & 1; // wires 9..11 -> tile bits
          else             bit = (l >> (w - 3)) & 1; // wires 12..15 -> bits 9..12
          zacc[w] += bit ? -prs : prs;
        }
      }
      #pragma unroll
      for (int w = 0; w < 16; ++w) {
        float vv = zacc[w];
        #pragma unroll
        for (int off = 32; off > 0; off >>= 1) vv += __shfl_xor(vv, off);
        zacc[w] = vv;
      }
      __syncthreads();                 // done reading amp; reuse LDS
      float* red = (float*)amp;
      const int lane = tid & 63, wv = tid >> 6;
      if (lane == 0) {
        #pragma unroll
        for (int w = 0; w < 16; ++w) red[wv * 16 + w] = zacc[w];
      }
      __syncthreads();
      if (tid < 16) {
        float s = 0.f;
        #pragma unroll
        for (int k = 0; k < 8; ++k) s += red[k * 16 + tid];
        zpart[blockIdx.x * 16 + tid] = s;
      }
    }
  }
}

// ---------------- epilogue: z reduce over tiles, logits, log_softmax ----------------
__global__ __launch_bounds__(64)
void final_kernel(const float* __restrict__ zpart, const float* __restrict__ fc_w,
                  const float* __restrict__ fc_b, float* __restrict__ out) {
  const int b = blockIdx.x, lane = threadIdx.x;
  float z = 0.f;
  if (lane < 16) {
    #pragma unroll
    for (int t = 0; t < NTILES; ++t) z += zpart[(b * NTILES + t) * 16 + lane];
  }
  float acc = (lane < NC) ? fc_b[lane] : -1e30f;
  #pragma unroll
  for (int w = 0; w < 16; ++w) {
    float zw = __shfl(z, w);
    if (lane < NC) acc += fc_w[lane * 16 + w] * zw;
  }
  float m = -1e30f;
  #pragma unroll
  for (int j = 0; j < NC; ++j) m = fmaxf(m, __shfl(acc, j));
  float e = (lane < NC) ? expf(acc - m) : 0.f;
  float s = 0.f;
  #pragma unroll
  for (int j = 0; j < NC; ++j) s += __shfl(e, j);
  if (lane < NC) out[b * NC + lane] = acc - m - logf(s);
}

extern "C" void kernel_launch(void* const* d_in, const int* in_sizes, int n_in,
                              void* d_out, int out_size, void* d_ws, size_t ws_size,
                              hipStream_t stream) {
  const float* x    = (const float*)d_in[0];
  const float* rot  = (const float*)d_in[1];
  const float* crx  = (const float*)d_in[2];
  const float* fc_w = (const float*)d_in[3];
  const float* fc_b = (const float*)d_in[4];
  float* out = (float*)d_out;

  char* ws = (char*)d_ws;
  float2* state   = (float2*)ws;                                     // 33554432 B
  float2* gates1q = (float2*)(ws + 33554432);                        // 163840 B
  float2* crxcs   = (float2*)(ws + 33554432 + 163840);               // 640 B (pad 1024)
  float*  zpart   = (float*)(ws + 33554432 + 163840 + 1024);         // 32768 B

  precompute_kernel<<<21, 256, 0, stream>>>(x, rot, crx, gates1q, crxcs);

  const int G = NB * NTILES;
  pass_kernel<0, true,  false, 0><<<G, THREADS, 0, stream>>>(gates1q, crxcs, state, zpart);
  pass_kernel<0, false, false, 1><<<G, THREADS, 0, stream>>>(gates1q, crxcs, state, zpart);
  pass_kernel<1, false, false, 0><<<G, THREADS, 0, stream>>>(gates1q, crxcs, state, zpart);
  pass_kernel<1, false, false, 1><<<G, THREADS, 0, stream>>>(gates1q, crxcs, state, zpart);
  pass_kernel<2, false, false, 0><<<G, THREADS, 0, stream>>>(gates1q, crxcs, state, zpart);
  pass_kernel<2, false, false, 1><<<G, THREADS, 0, stream>>>(gates1q, crxcs, state, zpart);
  pass_kernel<3, false, false, 0><<<G, THREADS, 0, stream>>>(gates1q, crxcs, state, zpart);
  pass_kernel<3, false, false, 1><<<G, THREADS, 0, stream>>>(gates1q, crxcs, state, zpart);
  pass_kernel<4, false, false, 0><<<G, THREADS, 0, stream>>>(gates1q, crxcs, state, zpart);
  pass_kernel<4, false, true,  1><<<G, THREADS, 0, stream>>>(gates1q, crxcs, state, zpart);

  final_kernel<<<NB, 64, 0, stream>>>(zpart, fc_w, fc_b, out);
}

// Round 6
// 235.282 us; speedup vs baseline: 1.4652x; 1.1907x over previous
//
#include <hip/hip_runtime.h>
#include <math.h>

#define NQ 16
#define NL 5
#define NB 64
#define NC 10
#define TA 256      // A-pass threads (tile 4096 amps, 32 KB LDS)
#define TB 512      // B-pass threads

__device__ __forceinline__ float2 cmul(float2 a, float2 b) {
  return make_float2(a.x*b.x - a.y*b.y, a.x*b.y + a.y*b.x);
}
__device__ __forceinline__ float2 cadd(float2 a, float2 b) {
  return make_float2(a.x + b.x, a.y + b.y);
}
// LDS swizzle (12-bit domain): phys = i ^ ((i>>4)&0xF) ^ (((i>>8)&1)<<4).
// Conflict-free per half-wave for P1 write (i=tid<<4|m), P2 r/w (bits{0..3,8..11}=tid,
// offs m<<4), P3 read (base=tid, offs m<<8). XOR-linear: sw2(a|b)=sw2(a)^sw2(b) for
// disjoint a,b.
__device__ __forceinline__ int sw2(int i) { return i ^ ((i >> 4) & 0xF) ^ (((i >> 8) & 1) << 4); }

// ---------------- precompute: fused U = Rot * RX per (b, layer, wire); CRX cos/sin
__global__ void precompute_kernel(const float* __restrict__ x, const float* __restrict__ rot,
                                  const float* __restrict__ crx,
                                  float2* __restrict__ gates1q, float2* __restrict__ crxcs) {
  int idx = blockIdx.x * blockDim.x + threadIdx.x;
  if (idx < NB * NL * NQ) {
    int w = idx % NQ; int n = (idx / NQ) % NL; int b = idx / (NQ * NL);
    float xv = x[b * NQ + w];
    float sx, cx; sincosf(0.5f * xv, &sx, &cx);
    float phi = rot[(n * NQ + w) * 3 + 0];
    float th  = rot[(n * NQ + w) * 3 + 1];
    float om  = rot[(n * NQ + w) * 3 + 2];
    float st, ct; sincosf(0.5f * th, &st, &ct);
    float sa, ca; sincosf(0.5f * (phi + om), &sa, &ca);
    float sd, cd; sincosf(0.5f * (phi - om), &sd, &cd);
    float2 r00 = make_float2( ca * ct, -sa * ct);
    float2 r01 = make_float2(-cd * st, -sd * st);
    float2 r10 = make_float2( cd * st, -sd * st);
    float2 r11 = make_float2( ca * ct,  sa * ct);
    float2 rc = make_float2(cx, 0.f), rs = make_float2(0.f, -sx);
    float2* dst = gates1q + (size_t)idx * 4;
    dst[0] = cadd(cmul(r00, rc), cmul(r01, rs));
    dst[1] = cadd(cmul(r00, rs), cmul(r01, rc));
    dst[2] = cadd(cmul(r10, rc), cmul(r11, rs));
    dst[3] = cadd(cmul(r10, rs), cmul(r11, rc));
  }
  int c = idx - NB * NL * NQ;
  if (c >= 0 && c < NL * NQ) {
    float s, cc; sincosf(0.5f * crx[c], &s, &cc);
    crxcs[c] = make_float2(cc, s);
  }
}

// ---------------- register-group gate primitives ----------------
template<int K, int GB>
__device__ __forceinline__ void g1q(float2* v, const float2* U) {
  #pragma unroll
  for (int m = 0; m < (1 << K); ++m) {
    if (!(m & (1 << GB))) {
      const int m2 = m | (1 << GB);
      float2 a = v[m], b = v[m2];
      v[m]  = cadd(cmul(U[0], a), cmul(U[1], b));
      v[m2] = cadd(cmul(U[2], a), cmul(U[3], b));
    }
  }
}
template<int K, int CP, int TP>
__device__ __forceinline__ void gcrx(float2* v, float c, float s) {
  #pragma unroll
  for (int m = 0; m < (1 << K); ++m) {
    if ((m & (1 << CP)) && !(m & (1 << TP))) {
      const int m2 = m | (1 << TP);
      float2 a = v[m], b = v[m2];
      v[m]  = make_float2(c * a.x + s * b.y, c * a.y - s * b.x);
      v[m2] = make_float2(c * b.x + s * a.y, c * b.y - s * a.x);
    }
  }
}
// plain RX on group-bit TP (ctrl-outside-group CRX; identity when c=1,s=0)
template<int K, int TP>
__device__ __forceinline__ void grx1(float2* v, float c, float s) {
  #pragma unroll
  for (int m = 0; m < (1 << K); ++m) {
    if (!(m & (1 << TP))) {
      const int m2 = m | (1 << TP);
      float2 a = v[m], b = v[m2];
      v[m]  = make_float2(c * a.x + s * b.y, c * a.y - s * b.x);
      v[m2] = make_float2(c * b.x + s * a.y, c * b.y - s * a.x);
    }
  }
}

template<int Bb>
__device__ __forceinline__ int ins0(int v) {
  return ((v >> Bb) << (Bb + 1)) | (v & ((1 << Bb) - 1));
}

__device__ __forceinline__ void loadU(const float2* __restrict__ G, int w, float2* U) {
  const float4* p = (const float4*)(G + w * 4);
  float4 a = p[0], b = p[1];
  U[0] = make_float2(a.x, a.y); U[1] = make_float2(a.z, a.w);
  U[2] = make_float2(b.x, b.y); U[3] = make_float2(b.z, b.w);
}

// ============ A-pass: wires 0..11 (1q 0..11, crx (0,1)..(10,11)) ============
// Tile = 4096 contiguous amps (bits 12..15 = t), 32 KB LDS, 256 threads.
// 3 LDS-touch phases, 2 barriers. grid: FIRST ? 64 : 1024, bid = t*64+b (XCD pin b%8).
template<int LAYER, bool FIRST>
__global__ __launch_bounds__(TA, 4)
void passA_kernel(const float2* __restrict__ gates1q, const float2* __restrict__ crxcs,
                  float2* __restrict__ state) {
  __shared__ __align__(16) float2 amp[4096];   // 32 KB
  const int tid = threadIdx.x;
  int b, t;
  if constexpr (FIRST) { b = blockIdx.x; t = 0; }
  else { t = blockIdx.x >> 6; b = blockIdx.x & 63; }
  const float2* G  = gates1q + (size_t)(b * NL + LAYER) * NQ * 4;
  const float2* CS = crxcs + LAYER * NQ;
  const size_t gbase = ((size_t)b << 16) | ((size_t)t << 12);

  float2 UA[4], UB[4], UC[4], UD[4];
  float2 v[16];

  // ---- P1: global -> regs (group = bits {0,1,2,3}, contiguous) -> gates -> LDS ----
  if constexpr (FIRST) {
    #pragma unroll
    for (int m = 0; m < 16; ++m) v[m] = make_float2(0.f, 0.f);
    if (tid == 0) v[0] = make_float2(1.f, 0.f);
  } else {
    const float4* st4 = (const float4*)(state + gbase + ((size_t)tid << 4));
    #pragma unroll
    for (int k = 0; k < 8; ++k) {
      float4 d = st4[k];
      v[2*k]   = make_float2(d.x, d.y);
      v[2*k+1] = make_float2(d.z, d.w);
    }
  }
  loadU(G,0,UA); loadU(G,1,UB); loadU(G,2,UC); loadU(G,3,UD);
  {
    float2 k0 = CS[0], k1 = CS[1], k2 = CS[2];
    g1q<4,0>(v,UA); g1q<4,1>(v,UB); g1q<4,2>(v,UC); g1q<4,3>(v,UD);
    gcrx<4,0,1>(v,k0.x,k0.y); gcrx<4,1,2>(v,k1.x,k1.y); gcrx<4,2,3>(v,k2.x,k2.y);
  }
  {
    const int sb = sw2(tid << 4);
    #pragma unroll
    for (int m = 0; m < 16; ++m) amp[sb ^ m] = v[m];   // sw2(l0|m) = sw2(l0)^m
  }
  __syncthreads();

  // ---- P2: LDS sweep, group = bits {4,5,6,7} ----
  loadU(G,4,UA); loadU(G,5,UB); loadU(G,6,UC); loadU(G,7,UD);
  {
    float2 k3 = CS[3], k0 = CS[4], k1 = CS[5], k2 = CS[6];
    const int base = (tid & 15) | ((tid >> 4) << 8);   // bits 0..3, 8..11
    const int sb = sw2(base);
    #pragma unroll
    for (int m = 0; m < 16; ++m) v[m] = amp[sb ^ (m * 17)];  // sw2(m<<4) = m<<4 | m
    g1q<4,0>(v,UA); g1q<4,1>(v,UB); g1q<4,2>(v,UC); g1q<4,3>(v,UD);
    const bool pd = (base >> 3) & 1;   // crx(3,4): ctrl = bit 3 (in base)
    grx1<4,0>(v, pd ? k3.x : 1.f, pd ? k3.y : 0.f);
    gcrx<4,0,1>(v,k0.x,k0.y); gcrx<4,1,2>(v,k1.x,k1.y); gcrx<4,2,3>(v,k2.x,k2.y);
    #pragma unroll
    for (int m = 0; m < 16; ++m) amp[sb ^ (m * 17)] = v[m];
  }
  __syncthreads();

  // ---- P3: LDS read, group = bits {8,9,10,11} -> gates -> global (coalesced) ----
  loadU(G,8,UA); loadU(G,9,UB); loadU(G,10,UC); loadU(G,11,UD);
  {
    float2 k3 = CS[7], k0 = CS[8], k1 = CS[9], k2 = CS[10];
    const int base = tid;              // bits 0..7
    const int sb = sw2(base);
    #pragma unroll
    for (int m = 0; m < 16; ++m)
      v[m] = amp[sb ^ ((m << 8) | ((m & 1) << 4))];    // sw2(m<<8)
    g1q<4,0>(v,UA); g1q<4,1>(v,UB); g1q<4,2>(v,UC); g1q<4,3>(v,UD);
    const bool pd = (base >> 7) & 1;   // crx(7,8): ctrl = bit 7 (in base)
    grx1<4,0>(v, pd ? k3.x : 1.f, pd ? k3.y : 0.f);
    gcrx<4,0,1>(v,k0.x,k0.y); gcrx<4,1,2>(v,k1.x,k1.y); gcrx<4,2,3>(v,k2.x,k2.y);
    float2* stw = state + gbase;
    #pragma unroll
    for (int m = 0; m < 16; ++m) stw[base | (m << 8)] = v[m];  // 8B/lane, coalesced per m
  }
}

// ============ B-pass: wires 12..15 + wrap (1q 12..15, crx (11,12)..(15,0)) ============
// Register-only: group = bits {0,12,13,14,15} (K=5, 32 amps/thread). No LDS, no barriers.
// grid = 256, bid = tb*64 + b; base bits 1..9 from tid, 10..11 from tb.
template<int LAYER, bool LFIRST, bool LAST>
__global__ __launch_bounds__(TB, 2)
void passB_kernel(const float2* __restrict__ gates1q, const float2* __restrict__ crxcs,
                  float2* __restrict__ state, float* __restrict__ zpart) {
  const int tid = threadIdx.x;
  const int tb = blockIdx.x >> 6, b = blockIdx.x & 63;
  const float2* G  = gates1q + (size_t)(b * NL + LAYER) * NQ * 4;
  const float2* CS = crxcs + LAYER * NQ;
  const int base = (tb << 10) | (tid << 1);   // amp bits 1..11 (bit0 is in the group)
  float4* st4 = (float4*)(state + (((size_t)b) << 16));

  // group index m = hi*2 + p0: pos0 = amp bit0 (wire0), pos1..4 = amp bits 12..15
  float2 v[32];
  #pragma unroll
  for (int hi = 0; hi < 16; ++hi) {
    if constexpr (LFIRST) {
      if (hi >= 1) {  // after layer-0 A-pass, amps with any of bits 12..15 set are zero
        v[2*hi] = make_float2(0.f, 0.f); v[2*hi+1] = make_float2(0.f, 0.f);
        continue;
      }
    }
    float4 d = st4[((hi << 12) | base) >> 1];
    v[2*hi]   = make_float2(d.x, d.y);
    v[2*hi+1] = make_float2(d.z, d.w);
  }

  float2 U[4];
  loadU(G,12,U); g1q<5,1>(v,U);
  loadU(G,13,U); g1q<5,2>(v,U);
  loadU(G,14,U); g1q<5,3>(v,U);
  loadU(G,15,U); g1q<5,4>(v,U);
  {
    float2 kB = CS[11];                 // crx(11,12): ctrl = bit 11 = tb bit1 (block-uniform)
    if (tb & 2) grx1<5,1>(v, kB.x, kB.y);
    float2 k0 = CS[12], k1 = CS[13], k2 = CS[14], kF = CS[15];
    gcrx<5,1,2>(v,k0.x,k0.y);           // crx(12,13)
    gcrx<5,2,3>(v,k1.x,k1.y);           // crx(13,14)
    gcrx<5,3,4>(v,k2.x,k2.y);           // crx(14,15)
    gcrx<5,4,0>(v,kF.x,kF.y);           // crx(15,0)
  }

  if constexpr (!LAST) {
    #pragma unroll
    for (int hi = 0; hi < 16; ++hi)
      st4[((hi << 12) | base) >> 1] =
        make_float4(v[2*hi].x, v[2*hi].y, v[2*hi+1].x, v[2*hi+1].y);
  } else {
    // Z-expectation partials; state never stored.
    float S[16], prtot = 0.f, s0 = 0.f;
    #pragma unroll
    for (int hi = 0; hi < 16; ++hi) {
      float p0 = v[2*hi].x*v[2*hi].x + v[2*hi].y*v[2*hi].y;
      float p1 = v[2*hi+1].x*v[2*hi+1].x + v[2*hi+1].y*v[2*hi+1].y;
      S[hi] = p0 + p1; prtot += S[hi]; s0 += p0 - p1;
    }
    float zacc[16];
    zacc[0] = s0;
    #pragma unroll
    for (int w = 1; w < 12; ++w) {
      int bit = (w < 10) ? ((tid >> (w - 1)) & 1) : ((tb >> (w - 10)) & 1);
      zacc[w] = bit ? -prtot : prtot;
    }
    #pragma unroll
    for (int w = 12; w < 16; ++w) {
      float s = 0.f;
      #pragma unroll
      for (int hi = 0; hi < 16; ++hi) s += ((hi >> (w - 12)) & 1) ? -S[hi] : S[hi];
      zacc[w] = s;
    }
    __shared__ float red[8][16];
    const int lane = tid & 63, wv = tid >> 6;
    #pragma unroll
    for (int w = 0; w < 16; ++w) {
      float vv = zacc[w];
      #pragma unroll
      for (int off = 32; off > 0; off >>= 1) vv += __shfl_xor(vv, off);
      if (lane == 0) red[wv][w] = vv;
    }
    __syncthreads();
    if (tid < 16) {
      float s = 0.f;
      #pragma unroll
      for (int k = 0; k < 8; ++k) s += red[k][tid];
      zpart[blockIdx.x * 16 + tid] = s;
    }
  }
}

// ---------------- epilogue: z reduce over 4 B-blocks, logits, log_softmax ----------------
__global__ __launch_bounds__(64)
void final_kernel(const float* __restrict__ zpart, const float* __restrict__ fc_w,
                  const float* __restrict__ fc_b, float* __restrict__ out) {
  const int b = blockIdx.x, lane = threadIdx.x;
  float z = 0.f;
  if (lane < 16) {
    #pragma unroll
    for (int tb = 0; tb < 4; ++tb) z += zpart[((tb << 6) | b) * 16 + lane];
  }
  float acc = (lane < NC) ? fc_b[lane] : -1e30f;
  #pragma unroll
  for (int w = 0; w < 16; ++w) {
    float zw = __shfl(z, w);
    if (lane < NC) acc += fc_w[lane * 16 + w] * zw;
  }
  float m = -1e30f;
  #pragma unroll
  for (int j = 0; j < NC; ++j) m = fmaxf(m, __shfl(acc, j));
  float e = (lane < NC) ? expf(acc - m) : 0.f;
  float s = 0.f;
  #pragma unroll
  for (int j = 0; j < NC; ++j) s += __shfl(e, j);
  if (lane < NC) out[b * NC + lane] = acc - m - logf(s);
}

extern "C" void kernel_launch(void* const* d_in, const int* in_sizes, int n_in,
                              void* d_out, int out_size, void* d_ws, size_t ws_size,
                              hipStream_t stream) {
  const float* x    = (const float*)d_in[0];
  const float* rot  = (const float*)d_in[1];
  const float* crx  = (const float*)d_in[2];
  const float* fc_w = (const float*)d_in[3];
  const float* fc_b = (const float*)d_in[4];
  float* out = (float*)d_out;

  char* ws = (char*)d_ws;
  float2* state   = (float2*)ws;                                     // 33554432 B
  float2* gates1q = (float2*)(ws + 33554432);                        // 163840 B
  float2* crxcs   = (float2*)(ws + 33554432 + 163840);               // 640 B (pad 1024)
  float*  zpart   = (float*)(ws + 33554432 + 163840 + 1024);         // 16384 B

  precompute_kernel<<<21, 256, 0, stream>>>(x, rot, crx, gates1q, crxcs);

  passA_kernel<0, true ><<<  64, TA, 0, stream>>>(gates1q, crxcs, state);
  passB_kernel<0, true,  false><<<256, TB, 0, stream>>>(gates1q, crxcs, state, zpart);
  passA_kernel<1, false><<<1024, TA, 0, stream>>>(gates1q, crxcs, state);
  passB_kernel<1, false, false><<<256, TB, 0, stream>>>(gates1q, crxcs, state, zpart);
  passA_kernel<2, false><<<1024, TA, 0, stream>>>(gates1q, crxcs, state);
  passB_kernel<2, false, false><<<256, TB, 0, stream>>>(gates1q, crxcs, state, zpart);
  passA_kernel<3, false><<<1024, TA, 0, stream>>>(gates1q, crxcs, state);
  passB_kernel<3, false, false><<<256, TB, 0, stream>>>(gates1q, crxcs, state, zpart);
  passA_kernel<4, false><<<1024, TA, 0, stream>>>(gates1q, crxcs, state);
  passB_kernel<4, false, true ><<<256, TB, 0, stream>>>(gates1q, crxcs, state, zpart);

  final_kernel<<<NB, 64, 0, stream>>>(zpart, fc_w, fc_b, out);
}